// Round 9
// baseline (164.851 us; speedup 1.0000x reference)
//
#include <hip/hip_runtime.h>
#include <stdint.h>

// LIF forward scan: u = 0.5*u + x[t] - 0.5*o ; o = (u - 0.5 > 0) ? 1 : 0
// x: [32, 8192, 200] f32, time contiguous. 262144 independent rows.
//
// R9 = R6's continuous gll pipeline + R1's clean coalesced stores.
//  - Each wave owns 64 rows; 32-step chunks (128B/row, 64B-line-aligned).
//  - Double-buffered wave-private LDS (2 x 8KB/wave); stage(ch+1) via 8
//    global_load_lds (1KB each, no data VGPRs -> cannot spill/corrupt:
//    R2/R5 collapsed, R8 corrupted with register pipelines).
//  - Counted WAITV(16): retires exactly gll(ch); gstore(ch-1)+gll(ch+1)
//    (16 ops) stay in flight. Stores only ever retire with >=2 iterations
//    of slack (R6's same-iter store-coupling was the 218us disaster).
//  - Loads in flight ~always (>=8KB/wave through the whole compute+store
//    phase; 10 waves/CU => ~80KB/CU >> ~12KB Little's-law need) -> no
//    convoying gaps (the 2.4TB/s ceiling of R1/R3/R5/R7).
//  - Stores: spikes go regs->LDS transpose->8 store insts, each covering
//    8 rows x 128B aligned pieces (16 full lines, zero partials): the
//    R1/R3-proven shape that measured WRITE=212MB exactly.
//  - LDS layout slot(seg c, row r) = c*64+r: gll dest linear per inst,
//    compute reads/writes contiguous 1KB per inst (conflict-free).
//  - No __syncthreads anywhere (wave-private buffers only).
// Arithmetic: __f*_rn forbids FMA contraction (bit-exact vs numpy order;
// a spike flip near threshold is absmax=1.0).

#define STEPS 200
#define TPB 128   // 2 waves per block

typedef __attribute__((address_space(3))) uint32_t lds_u32;
typedef __attribute__((address_space(1))) const uint32_t glb_u32;

#define WAITV(n) do { asm volatile("s_waitcnt vmcnt(" #n ")" ::: "memory"); \
                      __builtin_amdgcn_sched_barrier(0); } while (0)

__device__ __forceinline__ void lif_step(float& u, float& o, float xi) {
    float a = __fmul_rn(0.5f, u);
    float s = __fadd_rn(a, xi);
    float d = __fmul_rn(0.5f, o);
    u = __fsub_rn(s, d);
    o = (u > 0.5f) ? 1.0f : 0.0f;
}

// stage NS 16B-segs of all 64 rows: gll inst i fills slots [i*64, i*64+64)
// (linear: uniform base + lane*16); source = this lane's row, seg i.
template <int NS>
__device__ __forceinline__ void stage(const float* __restrict__ xlane,
                                      float4* buf, int t0) {
#pragma unroll
    for (int i = 0; i < NS; ++i)
        __builtin_amdgcn_global_load_lds((const glb_u32*)(xlane + t0 + i * 4),
                                         (lds_u32*)(buf + i * 64), 16, 0, 0);
}

// compute NS*4 steps for row `lane` out of buf, then coalesced store.
template <int NS>
__device__ __forceinline__ void comp_store(float4* buf, float* __restrict__ og,
                                           int lane, int t0, float& u, float& o) {
    float4 rx[NS];
#pragma unroll
    for (int c = 0; c < NS; ++c)           // contiguous 1KB ds_read_b128
        rx[c] = buf[c * 64 + lane];
#pragma unroll
    for (int c = 0; c < NS; ++c) {         // pure-register scan
        float4 v = rx[c];
        lif_step(u, o, v.x); float o0 = o;
        lif_step(u, o, v.y); float o1 = o;
        lif_step(u, o, v.z); float o2 = o;
        lif_step(u, o, v.w); float o3 = o;
        rx[c] = make_float4(o0, o1, o2, o3);
    }
#pragma unroll
    for (int c = 0; c < NS; ++c)           // spikes back, contiguous insts
        buf[c * 64 + lane] = rx[c];
    // transpose-read + store: inst i covers 8 rows x 128B aligned (NS=8)
#pragma unroll
    for (int i = 0; i < NS; ++i) {
        int f = i * 64 + lane;
        int r = (NS == 8) ? (f >> 3) : (f >> 1);
        int c = (NS == 8) ? (f & 7)  : (f & 1);
        float4 v = buf[c * 64 + r];
        *reinterpret_cast<float4*>(og + r * STEPS + t0 + c * 4) = v;
    }
}

__global__ __launch_bounds__(TPB) void lif_kernel(
    const float* __restrict__ x, float* __restrict__ out)
{
    __shared__ float4 tile[2 * 2 * 512];           // 2 waves x 2 bufs x 8KB = 32KB
    const int tid = threadIdx.x;
    const int w = tid >> 6, lane = tid & 63;
    const long long wrow0 = (long long)blockIdx.x * TPB + w * 64;
    const float* xlane = x + (wrow0 + lane) * STEPS;   // this lane's row
    float* og = out + wrow0 * STEPS;                   // wave's output base
    float4* bA = tile + (w * 2 + 0) * 512;
    float4* bB = tile + (w * 2 + 1) * 512;
    float u = 0.0f, o = 0.0f;

    // vmcnt bookkeeping (in-order retirement, loads+stores share counter):
    // steady iter: [8 gll ch+1][WAITV(16): retires gll(ch); newer = 8 gstore(ch-1)
    // + 8 gll(ch+1)][compute][8 gstore(ch)]. Stores retire with >=2 iters slack.
    stage<8>(xlane, bA, 0);
    stage<8>(xlane, bB, 32);  WAITV(8);  comp_store<8>(bA, og, lane, 0,   u, o);
    stage<8>(xlane, bA, 64);  WAITV(16); comp_store<8>(bB, og, lane, 32,  u, o);
    stage<8>(xlane, bB, 96);  WAITV(16); comp_store<8>(bA, og, lane, 64,  u, o);
    stage<8>(xlane, bA, 128); WAITV(16); comp_store<8>(bB, og, lane, 96,  u, o);
    stage<8>(xlane, bB, 160); WAITV(16); comp_store<8>(bA, og, lane, 128, u, o);
    stage<2>(xlane, bA, 192); WAITV(10); comp_store<8>(bB, og, lane, 160, u, o);
                              WAITV(8);  comp_store<2>(bA, og, lane, 192, u, o);
}

extern "C" void kernel_launch(void* const* d_in, const int* in_sizes, int n_in,
                              void* d_out, int out_size, void* d_ws, size_t ws_size,
                              hipStream_t stream)
{
    const float* x = (const float*)d_in[0];
    float* out = (float*)d_out;
    int nrows = in_sizes[0] / STEPS;       // 262144
    int grid = nrows / TPB;                // 2048 blocks of 2 waves
    lif_kernel<<<grid, TPB, 0, stream>>>(x, out);
}

// Round 10
// 160.162 us; speedup vs baseline: 1.0293x; 1.0293x over previous
//
#include <hip/hip_runtime.h>

// LIF forward scan: u = 0.5*u + x[t] - 0.5*o ; o = (u - 0.5 > 0) ? 1 : 0
// x: [32, 8192, 200] f32, time contiguous. 262144 independent rows.
//
// R10: bulk-MLP register scan -- the structure R1-R9 never tried.
// Synthesis of 9 rounds: every design that waited on memory once per small
// chunk (8-32 steps) landed at 130-220us regardless of mechanism (LDS
// convoy / wave-private / gll pipeline): per-wait latency exposure x many
// waits/row. Fix: amortize to ONE wait per 100 steps.
//  - 1 thread per row. No LDS, no barriers, no inline asm.
//  - Per half-row: 25 independent float4 loads issued back-to-back (bulk,
//    ~20KB/wave in flight, 25-deep MLP), then a 100-step register scan.
//    hipcc emits fine-grained vmcnt(24),(23).. so the scan starts when
//    rx[0] lands and overlaps the tail loads' latency.
//  - Single buffer, load-all-then-consume order: no prefetch-across-store
//    for the register allocator to collapse (R2/R5's failure) and no asm
//    fragility (R8's failure). Expect VGPR ~110 -> 16 waves/CU.
//  - Spike stores interleaved with the scan (one float4 per 4 steps),
//    per-lane strided; store->load coupling happens once per row only.
// Arithmetic: __f*_rn forbids FMA contraction (bit-exact vs numpy order;
// a spike flip near threshold is absmax=1.0).

#define STEPS 200

__device__ __forceinline__ void lif_step(float& u, float& o, float xi) {
    float a = __fmul_rn(0.5f, u);
    float s = __fadd_rn(a, xi);
    float d = __fmul_rn(0.5f, o);
    u = __fsub_rn(s, d);
    o = (u > 0.5f) ? 1.0f : 0.0f;
}

// one 100-step pass: 25 bulk loads, register scan, interleaved stores
__device__ __forceinline__ void half_pass(const float* __restrict__ xr,
                                          float* __restrict__ orw,
                                          float& u, float& o) {
    float4 rx[25];
#pragma unroll
    for (int k = 0; k < 25; ++k)
        rx[k] = *reinterpret_cast<const float4*>(xr + k * 4);
#pragma unroll
    for (int k = 0; k < 25; ++k) {
        float4 v = rx[k];
        lif_step(u, o, v.x); float o0 = o;
        lif_step(u, o, v.y); float o1 = o;
        lif_step(u, o, v.z); float o2 = o;
        lif_step(u, o, v.w); float o3 = o;
        *reinterpret_cast<float4*>(orw + k * 4) = make_float4(o0, o1, o2, o3);
    }
}

__global__ __launch_bounds__(256) void lif_kernel(const float* __restrict__ x,
                                                  float* __restrict__ out)
{
    const long long row = (long long)blockIdx.x * 256 + threadIdx.x;
    const float* xr = x + row * STEPS;
    float* orw = out + row * STEPS;
    float u = 0.0f, o = 0.0f;
    half_pass(xr, orw, u, o);
    half_pass(xr + 100, orw + 100, u, o);
}

extern "C" void kernel_launch(void* const* d_in, const int* in_sizes, int n_in,
                              void* d_out, int out_size, void* d_ws, size_t ws_size,
                              hipStream_t stream)
{
    const float* x = (const float*)d_in[0];
    float* out = (float*)d_out;
    int nrows = in_sizes[0] / STEPS;       // 262144
    int grid = nrows / 256;                // 1024 blocks
    lif_kernel<<<grid, 256, 0, stream>>>(x, out);
}

// Round 11
// 106.597 us; speedup vs baseline: 1.5465x; 1.5025x over previous
//
#include <hip/hip_runtime.h>
#include <stdint.h>

// LIF forward scan: u = 0.5*u + x[t] - 0.5*o ; o = (u - 0.5 > 0) ? 1 : 0
// x: [32, 8192, 200] f32, time contiguous. 262144 independent rows.
//
// R11: spike outputs are BINARY -> accumulate them as bits (7 u32/row) and
// store once at the END. This empties the vmcnt queue of stores:
//  - Phase 1 (load+scan): the only VMEM ops are this lane's sequential
//    float4 row loads. Every compiler vmcnt wait retires a load right
//    behind the streaming front; with 16 waves/CU even shallow per-wave
//    MLP sustains HBM rate. (R4/R6/R9/R10 all died on load-waits that
//    transitively required scattered-store retirement -- in-order vmcnt.)
//  - Phase 2: bit-words -> wave-private LDS (2KB) -> expand -> the wave's
//    50KB output written as 50 perfectly contiguous 1KB store insts
//    (addr = base + 16*f, f = s*64+lane): zero partial lines, WRITE ideal
//    (R5/R6/R10's per-lane 16B stores amplified WRITE 1.3-1.5x).
//  - No barriers (wave-private LDS), no inline-asm loads (R8 corruption),
//    no deep register buffers for the allocator to collapse (R2/R5/R10).
//  - Bit-pack loop fully unrolled -> all wbits[] indices compile-time
//    (runtime-indexed arrays go to scratch).
// Arithmetic: __f*_rn forbids FMA contraction (bit-exact vs numpy order;
// a spike flip near threshold is absmax=1.0). u>0.5f == (u-0.5>0) exactly
// (Sterbenz for u in [0.25,1], exact alignment above) -- verified absmax=0
// in R1/R3/R5/R7/R9/R10 on this dataset.

#define STEPS 200
#define TPB 256

__device__ __forceinline__ void lif_step(float& u, float& o, float xi) {
    float a = __fmul_rn(0.5f, u);
    float s = __fadd_rn(a, xi);
    float d = __fmul_rn(0.5f, o);
    u = __fsub_rn(s, d);
    o = (u > 0.5f) ? 1.0f : 0.0f;
}

__global__ __launch_bounds__(TPB) void lif_kernel(const float* __restrict__ x,
                                                  float* __restrict__ out)
{
    __shared__ uint32_t bits[4][64][8];        // [wave][row][word], 8 KB/block
    const int tid = threadIdx.x;
    const int w = tid >> 6, lane = tid & 63;
    const long long wrow0 = (long long)blockIdx.x * TPB + w * 64;
    const float* xr = x + (wrow0 + lane) * STEPS;   // this lane's row

    float u = 0.0f, o = 0.0f;
    uint32_t wb0 = 0, wb1 = 0, wb2 = 0, wb3 = 0, wb4 = 0, wb5 = 0, wb6 = 0;

    // ---- phase 1: load + scan + bit-pack (loads are the ONLY VMEM ops) ----
#pragma unroll
    for (int g = 0; g < 50; ++g) {             // 4 steps per group
        float4 v = *reinterpret_cast<const float4*>(xr + g * 4);
        uint32_t nib = 0;
        lif_step(u, o, v.x); nib |= (u > 0.5f) ? 1u : 0u;
        lif_step(u, o, v.y); nib |= (u > 0.5f) ? 2u : 0u;
        lif_step(u, o, v.z); nib |= (u > 0.5f) ? 4u : 0u;
        lif_step(u, o, v.w); nib |= (u > 0.5f) ? 8u : 0u;
        const uint32_t sh = (uint32_t)((g & 7) * 4);
        switch (g >> 3) {                      // compile-time after unroll
            case 0: wb0 |= nib << sh; break;
            case 1: wb1 |= nib << sh; break;
            case 2: wb2 |= nib << sh; break;
            case 3: wb3 |= nib << sh; break;
            case 4: wb4 |= nib << sh; break;
            case 5: wb5 |= nib << sh; break;
            case 6: wb6 |= nib << sh; break;
        }
    }

    // ---- phase 2: bits -> wave-private LDS -> coalesced contiguous stores ----
    bits[w][lane][0] = wb0; bits[w][lane][1] = wb1; bits[w][lane][2] = wb2;
    bits[w][lane][3] = wb3; bits[w][lane][4] = wb4; bits[w][lane][5] = wb5;
    bits[w][lane][6] = wb6;
    // (compiler inserts lgkmcnt before dependent ds_reads; wave-private -> no barrier)

    float* ob = out + wrow0 * STEPS;           // wave's 50 KB output, contiguous
#pragma unroll
    for (int s = 0; s < 50; ++s) {
        int f = s * 64 + lane;                 // global float4 index in wave region
        int r = f / 50;                        // row (magic-mul)
        int c = f - r * 50;                    // segment 0..49
        uint32_t wd = bits[w][r][c >> 3];
        int sh = (c & 7) * 4;
        float4 v;
        v.x = (wd & (1u << sh))       ? 1.0f : 0.0f;
        v.y = (wd & (2u << sh))       ? 1.0f : 0.0f;
        v.z = (wd & (4u << sh))       ? 1.0f : 0.0f;
        v.w = (wd & (8u << sh))       ? 1.0f : 0.0f;
        *reinterpret_cast<float4*>(ob + f * 4) = v;   // base + 16B*f: contiguous
    }
}

extern "C" void kernel_launch(void* const* d_in, const int* in_sizes, int n_in,
                              void* d_out, int out_size, void* d_ws, size_t ws_size,
                              hipStream_t stream)
{
    const float* x = (const float*)d_in[0];
    float* out = (float*)d_out;
    int nrows = in_sizes[0] / STEPS;       // 262144
    int grid = nrows / TPB;                // 1024 blocks
    lif_kernel<<<grid, TPB, 0, stream>>>(x, out);
}

// Round 12
// 96.189 us; speedup vs baseline: 1.7138x; 1.1082x over previous
//
#include <hip/hip_runtime.h>
#include <stdint.h>

// LIF forward scan: u = 0.5*u + x[t] - 0.5*o ; o = (u - 0.5 > 0) ? 1 : 0
// x: [32, 8192, 200] f32, time contiguous. 262144 independent rows.
//
// R12 = R11's bit-packed deferred stores + COPY-SHAPED gll loads.
//  - R11 proved: stores out of the loop (bit-pack, 7 u32/row) -> WRITE
//    exactly ideal; remaining 84% VALU-idle = load latency exposure from
//    per-lane 16B loads touching 64 scattered lines per wave-inst.
//    (fillBufferAligned on the same machine: 6.9 TB/s with 8-full-lines
//    per inst -- that's the shape to copy.)
//  - Chunk = 64 rows x 32 steps (8KB). gll inst i covers the CONTIGUOUS
//    global kilobyte = rows 8i..8i+7's 128B stripes = 8 full aligned lines.
//  - Both-sides swizzle (linear gll dest): LDS slot s=i*64+l holds
//    row r=s>>3, c_sw=s&7, actual seg c = c_sw ^ (r&7); source address
//    pre-swizzled (lane-only: c=(l&7)^((l>>3)&7)); ds_read applies the
//    same XOR -> 8 words/bank on write AND read (minimum, conflict-free).
//  - vmcnt queue contains ONLY gll loads; counted WAITV(8) retires chunk
//    ch while ch+1's 8KB rides under the ~512-cyc scan. No barriers
//    (wave-private LDS), no register pipelines (R2/R5/R8/R10 lessons).
//  - 6x32-step chunks + 8-step tail; per chunk the 32 spikes fill exactly
//    one u32 word. Store phase = R11's: bits -> LDS -> 50 contiguous 1KB
//    store insts per wave (measured WRITE=204800KB ideal).
// Arithmetic: __f*_rn forbids FMA contraction (bit-exact vs numpy order).

#define STEPS 200
#define TPB 128   // 2 waves/block; 32 KB LDS -> 5 blocks/CU

typedef __attribute__((address_space(3))) uint32_t lds_u32;
typedef __attribute__((address_space(1))) const uint32_t glb_u32;

#define WAITV(n) do { asm volatile("s_waitcnt vmcnt(" #n ")" ::: "memory"); \
                      __builtin_amdgcn_sched_barrier(0); } while (0)

__device__ __forceinline__ void lif_step(float& u, float& o, float xi) {
    float a = __fmul_rn(0.5f, u);
    float s = __fadd_rn(a, xi);
    float d = __fmul_rn(0.5f, o);
    u = __fsub_rn(s, d);
    o = (u > 0.5f) ? 1.0f : 0.0f;
}

// stage one 32-step chunk: 8 gll, each a contiguous 1KB global range
// (rows 8i..8i+7, this chunk's 128B stripes). src_base is the per-lane
// pre-swizzled base; inst i advances 8 rows; t0 selects the time window.
__device__ __forceinline__ void stage32(const float* __restrict__ src_base,
                                        float4* buf, int t0) {
#pragma unroll
    for (int i = 0; i < 8; ++i)
        __builtin_amdgcn_global_load_lds((const glb_u32*)(src_base + i * 8 * STEPS + t0),
                                         (lds_u32*)(buf + i * 64), 16, 0, 0);
}

// tail: 8 steps, 2 gll (rows 32i + l>>1, seg l&1; no swizzle needed)
__device__ __forceinline__ void stage8(const float* __restrict__ srcT,
                                       float4* buf) {
#pragma unroll
    for (int i = 0; i < 2; ++i)
        __builtin_amdgcn_global_load_lds((const glb_u32*)(srcT + i * 32 * STEPS),
                                         (lds_u32*)(buf + i * 64), 16, 0, 0);
}

// scan one 32-step chunk for row `lane` out of swizzled buf -> one u32 word
__device__ __forceinline__ uint32_t scan32(const float4* buf, int lane,
                                           float& u, float& o) {
    const int sw = lane & 7;
    float4 rx[8];
#pragma unroll
    for (int c = 0; c < 8; ++c)
        rx[c] = buf[lane * 8 + (c ^ sw)];
    uint32_t wd = 0;
#pragma unroll
    for (int g = 0; g < 8; ++g) {
        float4 v = rx[g];
        lif_step(u, o, v.x); wd |= (u > 0.5f) ? (1u << (4 * g + 0)) : 0u;
        lif_step(u, o, v.y); wd |= (u > 0.5f) ? (1u << (4 * g + 1)) : 0u;
        lif_step(u, o, v.z); wd |= (u > 0.5f) ? (1u << (4 * g + 2)) : 0u;
        lif_step(u, o, v.w); wd |= (u > 0.5f) ? (1u << (4 * g + 3)) : 0u;
    }
    return wd;
}

__device__ __forceinline__ uint32_t scan8(const float4* buf, int lane,
                                          float& u, float& o) {
    float4 r0 = buf[lane * 2 + 0];
    float4 r1 = buf[lane * 2 + 1];
    uint32_t wd = 0;
    lif_step(u, o, r0.x); wd |= (u > 0.5f) ? 1u   : 0u;
    lif_step(u, o, r0.y); wd |= (u > 0.5f) ? 2u   : 0u;
    lif_step(u, o, r0.z); wd |= (u > 0.5f) ? 4u   : 0u;
    lif_step(u, o, r0.w); wd |= (u > 0.5f) ? 8u   : 0u;
    lif_step(u, o, r1.x); wd |= (u > 0.5f) ? 16u  : 0u;
    lif_step(u, o, r1.y); wd |= (u > 0.5f) ? 32u  : 0u;
    lif_step(u, o, r1.z); wd |= (u > 0.5f) ? 64u  : 0u;
    lif_step(u, o, r1.w); wd |= (u > 0.5f) ? 128u : 0u;
    return wd;
}

__global__ __launch_bounds__(TPB) void lif_kernel(const float* __restrict__ x,
                                                  float* __restrict__ out)
{
    __shared__ float4 tile[2 * 2 * 512];           // 2 waves x 2 bufs x 8KB = 32KB
    const int tid = threadIdx.x;
    const int w = tid >> 6, lane = tid & 63;
    const long long wrow0 = (long long)blockIdx.x * TPB + w * 64;
    const float* xb = x + wrow0 * STEPS;
    float4* bA = tile + (w * 2 + 0) * 512;
    float4* bB = tile + (w * 2 + 1) * 512;

    // per-lane pre-swizzled source bases
    const int rsub = lane >> 3;                    // row within 8-row group
    const int csub = (lane & 7) ^ (rsub & 7);      // inverse-swizzled segment
    const float* srcS = xb + rsub * STEPS + csub * 4;
    const float* srcT = xb + (lane >> 1) * STEPS + (lane & 1) * 4 + 192;

    float u = 0.0f, o = 0.0f;
    uint32_t w0, w1, w2, w3, w4, w5, w6;

    // pipeline: queue only ever holds gll loads; stores all deferred
    stage32(srcS, bA, 0);
    stage32(srcS, bB, 32);   WAITV(8); w0 = scan32(bA, lane, u, o);
    stage32(srcS, bA, 64);   WAITV(8); w1 = scan32(bB, lane, u, o);
    stage32(srcS, bB, 96);   WAITV(8); w2 = scan32(bA, lane, u, o);
    stage32(srcS, bA, 128);  WAITV(8); w3 = scan32(bB, lane, u, o);
    stage32(srcS, bB, 160);  WAITV(8); w4 = scan32(bA, lane, u, o);
    stage8(srcT, bA);        WAITV(2); w5 = scan32(bB, lane, u, o);
                             WAITV(0); w6 = scan8(bA, lane, u, o);

    // ---- store phase: bits -> wave-private LDS -> 50 contiguous 1KB stores ----
    uint32_t* bits = reinterpret_cast<uint32_t*>(bB);   // 64 rows x 8 u32 slots
    bits[lane * 8 + 0] = w0; bits[lane * 8 + 1] = w1; bits[lane * 8 + 2] = w2;
    bits[lane * 8 + 3] = w3; bits[lane * 8 + 4] = w4; bits[lane * 8 + 5] = w5;
    bits[lane * 8 + 6] = w6;
    // same-wave DS ordering + compiler lgkmcnt: no barrier needed

    float* ob = out + wrow0 * STEPS;               // wave's 50KB output
#pragma unroll
    for (int s = 0; s < 50; ++s) {
        int f = s * 64 + lane;                     // float4 index in wave region
        int r = f / 50;                            // row (magic-mul)
        int c = f - r * 50;                        // segment 0..49
        uint32_t wd = bits[r * 8 + (c >> 3)];
        int sh = (c & 7) * 4;
        float4 v;
        v.x = (wd & (1u << sh)) ? 1.0f : 0.0f;
        v.y = (wd & (2u << sh)) ? 1.0f : 0.0f;
        v.z = (wd & (4u << sh)) ? 1.0f : 0.0f;
        v.w = (wd & (8u << sh)) ? 1.0f : 0.0f;
        *reinterpret_cast<float4*>(ob + f * 4) = v;   // contiguous: base + 16B*f
    }
}

extern "C" void kernel_launch(void* const* d_in, const int* in_sizes, int n_in,
                              void* d_out, int out_size, void* d_ws, size_t ws_size,
                              hipStream_t stream)
{
    const float* x = (const float*)d_in[0];
    float* out = (float*)d_out;
    int nrows = in_sizes[0] / STEPS;       // 262144
    int grid = nrows / TPB;                // 2048 blocks of 2 waves
    lif_kernel<<<grid, TPB, 0, stream>>>(x, out);
}

// Round 13
// 95.439 us; speedup vs baseline: 1.7273x; 1.0079x over previous
//
#include <hip/hip_runtime.h>
#include <stdint.h>

// LIF forward scan: u = 0.5*u + x[t] - 0.5*o ; o = (u - 0.5 > 0) ? 1 : 0
// x: [32, 8192, 200] f32, time contiguous. 262144 independent rows.
//
// R13 = R12 skeleton (copy-shaped gll loads, loads-only vmcnt queue,
// bit-packed deferred coalesced stores) + depth-3 pipeline + fma scan.
//  - 16-step chunks (4KB), 4 wave-private buffers: stage ch+3 while
//    scanning ch -> wait-target age ~3 scan-phases (~1100cyc) > 900cyc
//    HBM latency (R12's depth-1 exposed ~300cyc/chunk -> 55% HBM duty).
//    12KB/wave in flight continuously; 10 waves/CU (32KB/block, TPB=128).
//  - gll inst = 16 rows x 64B stripes = 16 full aligned lines (copy shape).
//    Both-sides swizzle: linear gll dest; source seg (l&3)^((l>>3)&3);
//    LDS slot(r,c) = r*4 + (c^((r>>1)&3)) -> read phase covers all 8
//    bank-groups per seg (R12's swizzle covered only 4).
//  - fma scan: 0.5*u and o*Vth are EXACT products, so
//    u' = __fmaf_rn(0.5,u,x) then __fsub_rn(u',d) with d=o*Vth in {0,0.5}
//    is bit-identical to numpy's ((0.5u)+x)-(0.5o) order, with a 2-op
//    dependent chain (8cyc) instead of 4-op (R12) per step.
//  - Spikes -> bits (16/chunk, packed 2 chunks/u32, 7 u32/row); store
//    phase = R11/R12's proven 50 contiguous 1KB stores (WRITE ideal).
//  - No barriers (wave-private LDS), no register pipelines.

#define STEPS 200
#define TPB 128   // 2 waves/block; 32 KB LDS -> 5 blocks/CU

typedef __attribute__((address_space(3))) uint32_t lds_u32;
typedef __attribute__((address_space(1))) const uint32_t glb_u32;

#define WAITV(n) do { asm volatile("s_waitcnt vmcnt(" #n ")" ::: "memory"); \
                      __builtin_amdgcn_sched_barrier(0); } while (0)

// one step: t = fma(0.5,u,x); u = t - d; d = spike ? 0.5 : 0; bit into m
__device__ __forceinline__ void lif1(float xi, float& u, float& d,
                                     uint32_t& m, uint32_t bit) {
    float t = __fmaf_rn(0.5f, u, xi);
    u = __fsub_rn(t, d);
    bool sp = (u > 0.5f);
    d = sp ? 0.5f : 0.0f;
    m |= sp ? bit : 0u;
}

// stage one 16-step chunk: 4 gll, each covering rows 16i..16i+15's
// contiguous 64B stripes (16 full lines). src_base is per-lane pre-swizzled.
__device__ __forceinline__ void stage16(const float* __restrict__ src_base,
                                        float4* buf, int t0) {
#pragma unroll
    for (int i = 0; i < 4; ++i)
        __builtin_amdgcn_global_load_lds((const glb_u32*)(src_base + i * 16 * STEPS + t0),
                                         (lds_u32*)(buf + i * 64), 16, 0, 0);
}

// tail: 8 steps, 2 gll (rows 32i + (l>>1), seg l&1, t0=192; linear layout)
__device__ __forceinline__ void stage8(const float* __restrict__ srcT,
                                       float4* buf) {
#pragma unroll
    for (int i = 0; i < 2; ++i)
        __builtin_amdgcn_global_load_lds((const glb_u32*)(srcT + i * 32 * STEPS),
                                         (lds_u32*)(buf + i * 64), 16, 0, 0);
}

// scan one 16-step chunk for row `lane` -> 16-bit spike mask
__device__ __forceinline__ uint32_t scan16(const float4* buf, int lane,
                                           float& u, float& d) {
    const int sw = (lane >> 1) & 3;
    float4 rx[4];
#pragma unroll
    for (int c = 0; c < 4; ++c)
        rx[c] = buf[lane * 4 + (c ^ sw)];
    uint32_t m = 0;
#pragma unroll
    for (int g = 0; g < 4; ++g) {
        lif1(rx[g].x, u, d, m, 1u << (4 * g + 0));
        lif1(rx[g].y, u, d, m, 1u << (4 * g + 1));
        lif1(rx[g].z, u, d, m, 1u << (4 * g + 2));
        lif1(rx[g].w, u, d, m, 1u << (4 * g + 3));
    }
    return m;
}

__device__ __forceinline__ uint32_t scan8(const float4* buf, int lane,
                                          float& u, float& d) {
    float4 r0 = buf[lane * 2 + 0];
    float4 r1 = buf[lane * 2 + 1];
    uint32_t m = 0;
    lif1(r0.x, u, d, m, 1u);   lif1(r0.y, u, d, m, 2u);
    lif1(r0.z, u, d, m, 4u);   lif1(r0.w, u, d, m, 8u);
    lif1(r1.x, u, d, m, 16u);  lif1(r1.y, u, d, m, 32u);
    lif1(r1.z, u, d, m, 64u);  lif1(r1.w, u, d, m, 128u);
    return m;
}

__global__ __launch_bounds__(TPB) void lif_kernel(const float* __restrict__ x,
                                                  float* __restrict__ out)
{
    __shared__ float4 tile[2 * 4 * 256];           // 2 waves x 4 bufs x 4KB = 32KB
    const int tid = threadIdx.x;
    const int w = tid >> 6, lane = tid & 63;
    const long long wrow0 = (long long)blockIdx.x * TPB + w * 64;
    const float* xb = x + wrow0 * STEPS;
    float4* B[4] = { tile + w * 1024,        tile + w * 1024 + 256,
                     tile + w * 1024 + 512,  tile + w * 1024 + 768 };

    // per-lane pre-swizzled source bases
    const float* srcS = xb + (lane >> 2) * STEPS + (((lane & 3) ^ ((lane >> 3) & 3)) << 2);
    const float* srcT = xb + (lane >> 1) * STEPS + ((lane & 1) << 2) + 192;

    float u = 0.0f, d = 0.0f;                      // d = o*Vth in {0, 0.5}
    uint32_t m;
    uint32_t w0, w1, w2, w3, w4, w5, w6;

    // prologue: 3 chunks in flight (12 gll)
    stage16(srcS, B[0], 0);
    stage16(srcS, B[1], 16);
    stage16(srcS, B[2], 32);

    // steady: stage ch+3, WAITV(12) retires ch (queue holds ONLY loads)
    stage16(srcS, B[3], 48);   WAITV(12); w0  = scan16(B[0], lane, u, d);
    stage16(srcS, B[0], 64);   WAITV(12); w0 |= scan16(B[1], lane, u, d) << 16;
    stage16(srcS, B[1], 80);   WAITV(12); w1  = scan16(B[2], lane, u, d);
    stage16(srcS, B[2], 96);   WAITV(12); w1 |= scan16(B[3], lane, u, d) << 16;
    stage16(srcS, B[3], 112);  WAITV(12); w2  = scan16(B[0], lane, u, d);
    stage16(srcS, B[0], 128);  WAITV(12); w2 |= scan16(B[1], lane, u, d) << 16;
    stage16(srcS, B[1], 144);  WAITV(12); w3  = scan16(B[2], lane, u, d);
    stage16(srcS, B[2], 160);  WAITV(12); w3 |= scan16(B[3], lane, u, d) << 16;
    stage16(srcS, B[3], 176);  WAITV(12); w4  = scan16(B[0], lane, u, d);
    stage8(srcT, B[0]);        WAITV(10); w4 |= scan16(B[1], lane, u, d) << 16;
                               WAITV(6);  w5  = scan16(B[2], lane, u, d);
                               WAITV(2);  w5 |= scan16(B[3], lane, u, d) << 16;
                               WAITV(0);  w6  = scan8(B[0], lane, u, d);

    // ---- store phase: bits -> wave-private LDS -> 50 contiguous 1KB stores ----
    uint32_t* bits = reinterpret_cast<uint32_t*>(B[1]);  // 64 rows x 8 u32
    bits[lane * 8 + 0] = w0; bits[lane * 8 + 1] = w1; bits[lane * 8 + 2] = w2;
    bits[lane * 8 + 3] = w3; bits[lane * 8 + 4] = w4; bits[lane * 8 + 5] = w5;
    bits[lane * 8 + 6] = w6;
    // same-wave DS ordering + compiler lgkmcnt: no barrier needed

    float* ob = out + wrow0 * STEPS;               // wave's 50KB output
#pragma unroll
    for (int s = 0; s < 50; ++s) {
        int f = s * 64 + lane;                     // float4 index in wave region
        int r = f / 50;                            // row (magic-mul)
        int c = f - r * 50;                        // segment 0..49 (4 steps)
        uint32_t wd = bits[r * 8 + (c >> 3)] >> (((c >> 2) & 1) * 16 + (c & 3) * 4);
        float4 v;
        v.x = (wd & 1u) ? 1.0f : 0.0f;
        v.y = (wd & 2u) ? 1.0f : 0.0f;
        v.z = (wd & 4u) ? 1.0f : 0.0f;
        v.w = (wd & 8u) ? 1.0f : 0.0f;
        *reinterpret_cast<float4*>(ob + f * 4) = v;   // contiguous: base + 16B*f
    }
}

extern "C" void kernel_launch(void* const* d_in, const int* in_sizes, int n_in,
                              void* d_out, int out_size, void* d_ws, size_t ws_size,
                              hipStream_t stream)
{
    const float* x = (const float*)d_in[0];
    float* out = (float*)d_out;
    int nrows = in_sizes[0] / STEPS;       // 262144
    int grid = nrows / TPB;                // 2048 blocks of 2 waves
    lif_kernel<<<grid, TPB, 0, stream>>>(x, out);
}